// Round 1
// baseline (498.143 us; speedup 1.0000x reference)
//
#include <hip/hip_runtime.h>

typedef float f32x4 __attribute__((ext_vector_type(4)));
typedef short s16x8 __attribute__((ext_vector_type(8)));
typedef unsigned short u16;

#define MFMA16 __builtin_amdgcn_mfma_f32_16x16x32_bf16
#define SCALE 0.17677669529663687f  // 32^-0.5

__device__ __forceinline__ u16 f2b(float f) {
  union { float f; unsigned u; } x; x.f = f;
  unsigned r = x.u + 0x7fffu + ((x.u >> 16) & 1u);
  return (u16)(r >> 16);
}

__device__ __forceinline__ float grp_max16(float v) {
  v = fmaxf(v, __shfl_xor(v, 1));
  v = fmaxf(v, __shfl_xor(v, 2));
  v = fmaxf(v, __shfl_xor(v, 4));
  v = fmaxf(v, __shfl_xor(v, 8));
  return v;
}
__device__ __forceinline__ float grp_sum16(float v) {
  v += __shfl_xor(v, 1);
  v += __shfl_xor(v, 2);
  v += __shfl_xor(v, 4);
  v += __shfl_xor(v, 8);
  return v;
}

// ---------------- weight transpose + bf16 cast: WT[j][d] = bf16(W[d][j]) ----
__global__ __launch_bounds__(256) void wtrans_kernel(
    const float* __restrict__ Wq, const float* __restrict__ Wk,
    const float* __restrict__ Wv, const float* __restrict__ Wo,
    u16* __restrict__ WqT, u16* __restrict__ WkT,
    u16* __restrict__ WvT, u16* __restrict__ WoT) {
  const float* src; u16* dst;
  switch (blockIdx.x) {
    case 0: src = Wq; dst = WqT; break;
    case 1: src = Wk; dst = WkT; break;
    case 2: src = Wv; dst = WvT; break;
    default: src = Wo; dst = WoT; break;
  }
  int j = blockIdx.y;
  int d = threadIdx.x;
  dst[j * 256 + d] = f2b(src[d * 256 + j]);
}

// ---------------- xq passthrough (output 1) --------------------------------
__global__ __launch_bounds__(256) void copyxq_kernel(const float* __restrict__ xq,
                                                     float* __restrict__ dst) {
  int i = blockIdx.x * 256 + threadIdx.x;
  dst[i] = xq[i];
}

// ---------------- QKV projection: bf16 MFMA GEMM ---------------------------
// C = Z[8192,256] @ W[256,256]; q,k stored row-major bf16; v stored transposed
__global__ __launch_bounds__(256) void proj_kernel(
    const float* __restrict__ zq, const float* __restrict__ zk,
    const float* __restrict__ zv,
    const u16* __restrict__ WqT, const u16* __restrict__ WkT,
    const u16* __restrict__ WvT,
    u16* __restrict__ qb, u16* __restrict__ kb, u16* __restrict__ vT) {
  const int mat = blockIdx.z;
  const float* Z = (mat == 0) ? zq : (mat == 1) ? zk : zv;
  const u16* WT = (mat == 0) ? WqT : (mat == 1) ? WkT : WvT;
  const int n0 = blockIdx.x * 64;
  const int j0 = blockIdx.y * 64;
  const int tid = threadIdx.x;
  const int lane = tid & 63, wid = tid >> 6;
  const int l15 = lane & 15, lg = lane >> 4;
  const int wn = wid & 1, wj = wid >> 1;

  __shared__ u16 As[64][40];
  __shared__ u16 Bs[64][40];

  f32x4 acc[2][2];
  #pragma unroll
  for (int a = 0; a < 2; ++a)
    #pragma unroll
    for (int b = 0; b < 2; ++b) acc[a][b] = (f32x4){0.f, 0.f, 0.f, 0.f};

  for (int ks = 0; ks < 8; ++ks) {
    const int d0 = ks * 32;
    const int r = tid >> 2, cb = (tid & 3) * 8;
    const float* zsrc = &Z[(size_t)(n0 + r) * 256 + d0 + cb];
    s16x8 t;
    #pragma unroll
    for (int j = 0; j < 8; ++j) t[j] = (short)f2b(zsrc[j]);
    *(s16x8*)&As[r][cb] = t;
    *(s16x8*)&Bs[r][cb] = *(const s16x8*)&WT[(size_t)(j0 + r) * 256 + d0 + cb];
    __syncthreads();
    s16x8 a0 = *(const s16x8*)&As[wn * 32 + l15][lg * 8];
    s16x8 a1 = *(const s16x8*)&As[wn * 32 + 16 + l15][lg * 8];
    s16x8 b0 = *(const s16x8*)&Bs[wj * 32 + l15][lg * 8];
    s16x8 b1 = *(const s16x8*)&Bs[wj * 32 + 16 + l15][lg * 8];
    acc[0][0] = MFMA16(a0, b0, acc[0][0], 0, 0, 0);
    acc[0][1] = MFMA16(a0, b1, acc[0][1], 0, 0, 0);
    acc[1][0] = MFMA16(a1, b0, acc[1][0], 0, 0, 0);
    acc[1][1] = MFMA16(a1, b1, acc[1][1], 0, 0, 0);
    __syncthreads();
  }
  #pragma unroll
  for (int sn = 0; sn < 2; ++sn)
    #pragma unroll
    for (int sj = 0; sj < 2; ++sj)
      #pragma unroll
      for (int i = 0; i < 4; ++i) {
        int n = n0 + wn * 32 + sn * 16 + lg * 4 + i;
        int j = j0 + wj * 32 + sj * 16 + l15;
        u16 val = f2b(acc[sn][sj][i]);
        if (mat == 0) {
          qb[(size_t)n * 256 + j] = val;
        } else if (mat == 1) {
          kb[(size_t)n * 256 + j] = val;
        } else {
          int mm = n >> 10, nn = n & 1023;
          vT[((size_t)(mm * 256 + j)) * 1024 + nn] = val;
        }
      }
}

// ---------------- fused TE attention ---------------------------------------
// Block: (q-tile of 32, m). 512 threads = 8 waves. K-tiles of 64.
__global__ __launch_bounds__(512) void attn_kernel(
    const u16* __restrict__ qb, const u16* __restrict__ kb,
    const u16* __restrict__ vT,
    const float* __restrict__ xq, const float* __restrict__ xkv,
    const float* __restrict__ W1, const float* __restrict__ b1,
    const float* __restrict__ W2, const float* __restrict__ b2,
    u16* __restrict__ pre) {
  const int m = blockIdx.y;
  const int q0 = blockIdx.x * 32;
  const int tid = threadIdx.x;
  const int lane = tid & 63;
  const int wid = tid >> 6;       // 0..7
  const int l15 = lane & 15;
  const int lg = lane >> 4;       // 0..3
  const int qh = wid & 1;         // q half (both roles)
  const int k4 = wid >> 1;        // dots role: k quarter 0..3
  const int dh = (wid >> 1) & 1;  // PV role: d half
  const int hh = wid >> 2;        // PV role: head group 0..1

  __shared__ u16 q_s[32][264];
  __shared__ union { u16 k[64][264]; u16 p[8][32][72]; } kp;
  __shared__ u16 vT_s[256][72];
  __shared__ float pmax[4][32][8];
  __shared__ float psum[4][32][8];
  __shared__ float Mst[32][8];
  __shared__ float Lst[32][8];
  __shared__ float xq_s[32][2];
  __shared__ float xk_s[64][2];
  __shared__ float W1_s[10][32];
  __shared__ float b1_s[32];
  __shared__ float W2_s[32][8];
  __shared__ float b2_s[8];

  // init staging
  {
    int r = tid >> 4, cb = (tid & 15) * 16;
    const u16* src = &qb[((size_t)(m * 1024 + q0 + r)) * 256 + cb];
    *(s16x8*)&q_s[r][cb] = *(const s16x8*)&src[0];
    *(s16x8*)&q_s[r][cb + 8] = *(const s16x8*)&src[8];
  }
  if (tid < 64) xq_s[tid >> 1][tid & 1] = xq[((size_t)(m * 1024 + q0 + (tid >> 1))) * 2 + (tid & 1)];
  if (tid < 320) W1_s[tid >> 5][tid & 31] = W1[tid];
  if (tid < 32) b1_s[tid] = b1[tid];
  if (tid < 256) W2_s[tid >> 3][tid & 7] = W2[tid];
  if (tid < 8) b2_s[tid] = b2[tid];
  if (tid < 256) { Mst[tid >> 3][tid & 7] = -1e30f; Lst[tid >> 3][tid & 7] = 0.0f; }

  f32x4 acc_pv[4];
  #pragma unroll
  for (int hl = 0; hl < 4; ++hl) acc_pv[hl] = (f32x4){0.f, 0.f, 0.f, 0.f};

  __syncthreads();

  for (int kt = 0; kt < 16; ++kt) {
    const int k0 = kt * 64;
    // ---- S: stage k tile, vT tile, xk ----
    {
      int r = tid >> 3, cb = (tid & 7) * 32;
      const u16* src = &kb[((size_t)(m * 1024 + k0 + r)) * 256 + cb];
      #pragma unroll
      for (int j = 0; j < 4; ++j)
        *(s16x8*)&kp.k[r][cb + 8 * j] = *(const s16x8*)&src[8 * j];
    }
    {
      int d = tid >> 1, half = (tid & 1) * 32;
      const u16* src = &vT[((size_t)(m * 256 + d)) * 1024 + k0 + half];
      #pragma unroll
      for (int j = 0; j < 4; ++j)
        *(s16x8*)&vT_s[d][half + 8 * j] = *(const s16x8*)&src[8 * j];
    }
    if (tid < 128) xk_s[tid >> 1][tid & 1] = xkv[((size_t)(m * 1024 + k0 + (tid >> 1))) * 2 + (tid & 1)];
    __syncthreads();  // B1

    // ---- D: token dots (MFMA), MLP, tile max ----
    f32x4 dacc[8];
    #pragma unroll
    for (int h = 0; h < 8; ++h) {
      s16x8 a = *(const s16x8*)&q_s[qh * 16 + l15][h * 32 + lg * 8];
      s16x8 b = *(const s16x8*)&kp.k[k4 * 16 + l15][h * 32 + lg * 8];
      dacc[h] = MFMA16(a, b, (f32x4){0.f, 0.f, 0.f, 0.f}, 0, 0, 0);
    }
    #pragma unroll
    for (int h = 0; h < 8; ++h)
      #pragma unroll
      for (int i = 0; i < 4; ++i) dacc[h][i] *= SCALE;

    const int kk = k4 * 16 + l15;
    float dq0[4], dq1[4];
    #pragma unroll
    for (int i = 0; i < 4; ++i) {
      int qr = qh * 16 + lg * 4 + i;
      dq0[i] = xq_s[qr][0] - xk_s[kk][0];
      dq1[i] = xq_s[qr][1] - xk_s[kk][1];
    }
    float lgt[4][8];
    #pragma unroll
    for (int i = 0; i < 4; ++i)
      #pragma unroll
      for (int o = 0; o < 8; ++o) lgt[i][o] = b2_s[o];
    for (int c = 0; c < 32; ++c) {
      float w0 = W1_s[0][c], w1 = W1_s[1][c], bb = b1_s[c];
      float wh0 = W1_s[2][c], wh1 = W1_s[3][c], wh2 = W1_s[4][c], wh3 = W1_s[5][c];
      float wh4 = W1_s[6][c], wh5 = W1_s[7][c], wh6 = W1_s[8][c], wh7 = W1_s[9][c];
      float hv[4];
      #pragma unroll
      for (int i = 0; i < 4; ++i) {
        float s = bb + dq0[i] * w0 + dq1[i] * w1;
        s += dacc[0][i] * wh0; s += dacc[1][i] * wh1;
        s += dacc[2][i] * wh2; s += dacc[3][i] * wh3;
        s += dacc[4][i] * wh4; s += dacc[5][i] * wh5;
        s += dacc[6][i] * wh6; s += dacc[7][i] * wh7;
        hv[i] = fmaxf(s, 0.0f);
      }
      float w20 = W2_s[c][0], w21 = W2_s[c][1], w22 = W2_s[c][2], w23 = W2_s[c][3];
      float w24 = W2_s[c][4], w25 = W2_s[c][5], w26 = W2_s[c][6], w27 = W2_s[c][7];
      #pragma unroll
      for (int i = 0; i < 4; ++i) {
        lgt[i][0] += hv[i] * w20; lgt[i][1] += hv[i] * w21;
        lgt[i][2] += hv[i] * w22; lgt[i][3] += hv[i] * w23;
        lgt[i][4] += hv[i] * w24; lgt[i][5] += hv[i] * w25;
        lgt[i][6] += hv[i] * w26; lgt[i][7] += hv[i] * w27;
      }
    }
    #pragma unroll
    for (int h = 0; h < 8; ++h)
      #pragma unroll
      for (int i = 0; i < 4; ++i) dacc[h][i] = lgt[i][h];

    #pragma unroll
    for (int i = 0; i < 4; ++i) {
      int qr = qh * 16 + lg * 4 + i;
      #pragma unroll
      for (int h = 0; h < 8; ++h) {
        float mx = grp_max16(dacc[h][i]);
        if (l15 == 0) pmax[k4][qr][h] = mx;
      }
    }
    __syncthreads();  // B2

    // ---- P: p = exp(logit - m_new), partial sums, P -> LDS (bf16) ----
    #pragma unroll
    for (int i = 0; i < 4; ++i) {
      const int qr = qh * 16 + lg * 4 + i;
      #pragma unroll
      for (int h = 0; h < 8; ++h) {
        float mo = Mst[qr][h];
        float mt = fmaxf(fmaxf(pmax[0][qr][h], pmax[1][qr][h]),
                         fmaxf(pmax[2][qr][h], pmax[3][qr][h]));
        float mn = fmaxf(mo, mt);
        float pv = __expf(dacc[h][i] - mn);
        kp.p[h][qr][kk] = f2b(pv);
        float sm = grp_sum16(pv);
        if (l15 == 0) psum[k4][qr][h] = sm;
      }
    }
    // rescale this wave's PV accumulators (static reg indices only)
    #pragma unroll
    for (int hl = 0; hl < 4; ++hl) {
      const int h = hh * 4 + hl;
      #pragma unroll
      for (int i = 0; i < 4; ++i) {
        const int qr = qh * 16 + lg * 4 + i;
        float mo = Mst[qr][h];
        float mt = fmaxf(fmaxf(pmax[0][qr][h], pmax[1][qr][h]),
                         fmaxf(pmax[2][qr][h], pmax[3][qr][h]));
        float mn = fmaxf(mo, mt);
        acc_pv[hl][i] *= __expf(mo - mn);
      }
    }
    __syncthreads();  // B3

    // ---- V: state update (waves 0,1) + PV MFMA (all) ----
    if (wid < 2) {
      #pragma unroll
      for (int i = 0; i < 4; ++i) {
        int qr = qh * 16 + lg * 4 + i;
        #pragma unroll
        for (int h = 0; h < 8; ++h) {
          float mo = Mst[qr][h];
          float mt = fmaxf(fmaxf(pmax[0][qr][h], pmax[1][qr][h]),
                           fmaxf(pmax[2][qr][h], pmax[3][qr][h]));
          float mn = fmaxf(mo, mt);
          float al = __expf(mo - mn);
          float ln = al * Lst[qr][h] + psum[0][qr][h] + psum[1][qr][h] +
                     psum[2][qr][h] + psum[3][qr][h];
          if (l15 == 0) { Mst[qr][h] = mn; Lst[qr][h] = ln; }
        }
      }
    }
    #pragma unroll
    for (int hl = 0; hl < 4; ++hl) {
      int h = hh * 4 + hl;
      s16x8 a0 = *(const s16x8*)&kp.p[h][qh * 16 + l15][lg * 8];
      s16x8 a1 = *(const s16x8*)&kp.p[h][qh * 16 + l15][32 + lg * 8];
      s16x8 b0 = *(const s16x8*)&vT_s[h * 32 + dh * 16 + l15][lg * 8];
      s16x8 b1 = *(const s16x8*)&vT_s[h * 32 + dh * 16 + l15][32 + lg * 8];
      acc_pv[hl] = MFMA16(a0, b0, acc_pv[hl], 0, 0, 0);
      acc_pv[hl] = MFMA16(a1, b1, acc_pv[hl], 0, 0, 0);
    }
    __syncthreads();  // B4
  }

  // epilogue: normalize and store pre-projection output (bf16)
  #pragma unroll
  for (int hl = 0; hl < 4; ++hl) {
    int h = hh * 4 + hl;
    #pragma unroll
    for (int i = 0; i < 4; ++i) {
      int qr = qh * 16 + lg * 4 + i;
      float l = Lst[qr][h];
      float val = acc_pv[hl][i] / l;
      pre[((size_t)(m * 1024 + q0 + qr)) * 256 + h * 32 + dh * 16 + l15] = f2b(val);
    }
  }
}

// ---------------- output projection: out = pre @ Wout + bout (f32 out) -----
__global__ __launch_bounds__(256) void outp_kernel(
    const u16* __restrict__ pre, const u16* __restrict__ WoT,
    const float* __restrict__ bout, float* __restrict__ out) {
  const int n0 = blockIdx.x * 64;
  const int j0 = blockIdx.y * 64;
  const int tid = threadIdx.x;
  const int lane = tid & 63, wid = tid >> 6;
  const int l15 = lane & 15, lg = lane >> 4;
  const int wn = wid & 1, wj = wid >> 1;
  __shared__ u16 As[64][40];
  __shared__ u16 Bs[64][40];
  f32x4 acc[2][2];
  #pragma unroll
  for (int a = 0; a < 2; ++a)
    #pragma unroll
    for (int b = 0; b < 2; ++b) acc[a][b] = (f32x4){0.f, 0.f, 0.f, 0.f};

  for (int ks = 0; ks < 8; ++ks) {
    const int d0 = ks * 32;
    const int r = tid >> 2, cb = (tid & 3) * 8;
    *(s16x8*)&As[r][cb] = *(const s16x8*)&pre[(size_t)(n0 + r) * 256 + d0 + cb];
    *(s16x8*)&Bs[r][cb] = *(const s16x8*)&WoT[(size_t)(j0 + r) * 256 + d0 + cb];
    __syncthreads();
    s16x8 a0 = *(const s16x8*)&As[wn * 32 + l15][lg * 8];
    s16x8 a1 = *(const s16x8*)&As[wn * 32 + 16 + l15][lg * 8];
    s16x8 b0 = *(const s16x8*)&Bs[wj * 32 + l15][lg * 8];
    s16x8 b1 = *(const s16x8*)&Bs[wj * 32 + 16 + l15][lg * 8];
    acc[0][0] = MFMA16(a0, b0, acc[0][0], 0, 0, 0);
    acc[0][1] = MFMA16(a0, b1, acc[0][1], 0, 0, 0);
    acc[1][0] = MFMA16(a1, b0, acc[1][0], 0, 0, 0);
    acc[1][1] = MFMA16(a1, b1, acc[1][1], 0, 0, 0);
    __syncthreads();
  }
  #pragma unroll
  for (int sn = 0; sn < 2; ++sn)
    #pragma unroll
    for (int sj = 0; sj < 2; ++sj)
      #pragma unroll
      for (int i = 0; i < 4; ++i) {
        int n = n0 + wn * 32 + sn * 16 + lg * 4 + i;
        int j = j0 + wj * 32 + sj * 16 + l15;
        out[(size_t)n * 256 + j] = acc[sn][sj][i] + bout[j];
      }
}

extern "C" void kernel_launch(void* const* d_in, const int* in_sizes, int n_in,
                              void* d_out, int out_size, void* d_ws, size_t ws_size,
                              hipStream_t stream) {
  const float* zq = (const float*)d_in[0];
  const float* zk = (const float*)d_in[1];
  const float* zv = (const float*)d_in[2];
  const float* xq = (const float*)d_in[3];
  const float* xkv = (const float*)d_in[4];
  const float* Wq = (const float*)d_in[5];
  const float* Wk = (const float*)d_in[6];
  const float* Wv = (const float*)d_in[7];
  const float* Wo = (const float*)d_in[8];
  const float* bout = (const float*)d_in[9];
  const float* W1 = (const float*)d_in[10];
  const float* b1 = (const float*)d_in[11];
  const float* W2 = (const float*)d_in[12];
  const float* b2 = (const float*)d_in[13];
  float* out = (float*)d_out;

  char* ws = (char*)d_ws;
  u16* qb  = (u16*)(ws + (size_t)0);
  u16* kb  = (u16*)(ws + ((size_t)4 << 20));
  u16* vT  = (u16*)(ws + ((size_t)8 << 20));
  u16* pre = (u16*)(ws + ((size_t)12 << 20));
  u16* WqT = (u16*)(ws + ((size_t)16 << 20));
  u16* WkT = (u16*)(ws + ((size_t)16 << 20) + (128 << 10));
  u16* WvT = (u16*)(ws + ((size_t)16 << 20) + (256 << 10));
  u16* WoT = (u16*)(ws + ((size_t)16 << 20) + (384 << 10));

  wtrans_kernel<<<dim3(4, 256), dim3(256), 0, stream>>>(Wq, Wk, Wv, Wo, WqT, WkT, WvT, WoT);
  proj_kernel<<<dim3(128, 4, 3), dim3(256), 0, stream>>>(zq, zk, zv, WqT, WkT, WvT, qb, kb, vT);
  attn_kernel<<<dim3(32, 8), dim3(512), 0, stream>>>(qb, kb, vT, xq, xkv, W1, b1, W2, b2, pre);
  outp_kernel<<<dim3(128, 4), dim3(256), 0, stream>>>(pre, WoT, bout, out);
  copyxq_kernel<<<dim3(64), dim3(256), 0, stream>>>(xq, out + (size_t)8 * 1024 * 256);
}

// Round 2
// 265.682 us; speedup vs baseline: 1.8750x; 1.8750x over previous
//
#include <hip/hip_runtime.h>

typedef float f32x4 __attribute__((ext_vector_type(4)));
typedef short s16x8 __attribute__((ext_vector_type(8)));
typedef unsigned short u16;

#define MFMA16 __builtin_amdgcn_mfma_f32_16x16x32_bf16
#define SCALE 0.17677669529663687f  // 32^-0.5

__device__ __forceinline__ u16 f2b(float f) {
  union { float f; unsigned u; } x; x.f = f;
  unsigned r = x.u + 0x7fffu + ((x.u >> 16) & 1u);
  return (u16)(r >> 16);
}

__device__ __forceinline__ float grp_max16(float v) {
  v = fmaxf(v, __shfl_xor(v, 1));
  v = fmaxf(v, __shfl_xor(v, 2));
  v = fmaxf(v, __shfl_xor(v, 4));
  v = fmaxf(v, __shfl_xor(v, 8));
  return v;
}

// ---------------- weight transpose + bf16 cast: WT[j][d] = bf16(W[d][j]) ----
__global__ __launch_bounds__(256) void wtrans_kernel(
    const float* __restrict__ Wq, const float* __restrict__ Wk,
    const float* __restrict__ Wv, const float* __restrict__ Wo,
    u16* __restrict__ WqT, u16* __restrict__ WkT,
    u16* __restrict__ WvT, u16* __restrict__ WoT) {
  const float* src; u16* dst;
  switch (blockIdx.x) {
    case 0: src = Wq; dst = WqT; break;
    case 1: src = Wk; dst = WkT; break;
    case 2: src = Wv; dst = WvT; break;
    default: src = Wo; dst = WoT; break;
  }
  int j = blockIdx.y;
  int d = threadIdx.x;
  dst[j * 256 + d] = f2b(src[d * 256 + j]);
}

// ---------------- xq passthrough (output 1) --------------------------------
__global__ __launch_bounds__(256) void copyxq_kernel(const float* __restrict__ xq,
                                                     float* __restrict__ dst) {
  int i = blockIdx.x * 256 + threadIdx.x;
  dst[i] = xq[i];
}

// ---------------- QKV projection: bf16 MFMA GEMM ---------------------------
// C = Z[8192,256] @ W[256,256]; q (pre-scaled), k row-major bf16; v transposed
__global__ __launch_bounds__(256) void proj_kernel(
    const float* __restrict__ zq, const float* __restrict__ zk,
    const float* __restrict__ zv,
    const u16* __restrict__ WqT, const u16* __restrict__ WkT,
    const u16* __restrict__ WvT,
    u16* __restrict__ qb, u16* __restrict__ kb, u16* __restrict__ vT) {
  const int mat = blockIdx.z;
  const float* Z = (mat == 0) ? zq : (mat == 1) ? zk : zv;
  const u16* WT = (mat == 0) ? WqT : (mat == 1) ? WkT : WvT;
  const int n0 = blockIdx.x * 64;
  const int j0 = blockIdx.y * 64;
  const int tid = threadIdx.x;
  const int lane = tid & 63, wid = tid >> 6;
  const int l15 = lane & 15, lg = lane >> 4;
  const int wn = wid & 1, wj = wid >> 1;

  __shared__ u16 As[64][40];
  __shared__ u16 Bs[64][40];

  f32x4 acc[2][2];
  #pragma unroll
  for (int a = 0; a < 2; ++a)
    #pragma unroll
    for (int b = 0; b < 2; ++b) acc[a][b] = (f32x4){0.f, 0.f, 0.f, 0.f};

  for (int ks = 0; ks < 8; ++ks) {
    const int d0 = ks * 32;
    const int r = tid >> 2, cb = (tid & 3) * 8;
    const float* zsrc = &Z[(size_t)(n0 + r) * 256 + d0 + cb];
    s16x8 t;
    #pragma unroll
    for (int j = 0; j < 8; ++j) t[j] = (short)f2b(zsrc[j]);
    *(s16x8*)&As[r][cb] = t;
    *(s16x8*)&Bs[r][cb] = *(const s16x8*)&WT[(size_t)(j0 + r) * 256 + d0 + cb];
    __syncthreads();
    s16x8 a0 = *(const s16x8*)&As[wn * 32 + l15][lg * 8];
    s16x8 a1 = *(const s16x8*)&As[wn * 32 + 16 + l15][lg * 8];
    s16x8 b0 = *(const s16x8*)&Bs[wj * 32 + l15][lg * 8];
    s16x8 b1 = *(const s16x8*)&Bs[wj * 32 + 16 + l15][lg * 8];
    acc[0][0] = MFMA16(a0, b0, acc[0][0], 0, 0, 0);
    acc[0][1] = MFMA16(a0, b1, acc[0][1], 0, 0, 0);
    acc[1][0] = MFMA16(a1, b0, acc[1][0], 0, 0, 0);
    acc[1][1] = MFMA16(a1, b1, acc[1][1], 0, 0, 0);
    __syncthreads();
  }
  #pragma unroll
  for (int sn = 0; sn < 2; ++sn)
    #pragma unroll
    for (int sj = 0; sj < 2; ++sj)
      #pragma unroll
      for (int i = 0; i < 4; ++i) {
        int n = n0 + wn * 32 + sn * 16 + lg * 4 + i;
        int j = j0 + wj * 32 + sj * 16 + l15;
        float av = acc[sn][sj][i];
        if (mat == 0) av *= SCALE;  // fold softmax scale into q
        u16 val = f2b(av);
        if (mat == 0) {
          qb[(size_t)n * 256 + j] = val;
        } else if (mat == 1) {
          kb[(size_t)n * 256 + j] = val;
        } else {
          int mm = n >> 10, nn = n & 1023;
          vT[((size_t)(mm * 256 + j)) * 1024 + nn] = val;
        }
      }
}

// ---------------- fused TE attention ---------------------------------------
// Block: 16 queries of one m. 512 threads = 8 waves. K-tiles of 128.
// Wave roles: dots: k8 = wid (kk = wid*16+l15). PV/sum: head h = wid.
__global__ __launch_bounds__(512, 4) void attn_kernel(
    const u16* __restrict__ qb, const u16* __restrict__ kb,
    const u16* __restrict__ vT,
    const float* __restrict__ xq, const float* __restrict__ xkv,
    const float* __restrict__ W1, const float* __restrict__ b1,
    const float* __restrict__ W2, const float* __restrict__ b2,
    u16* __restrict__ pre) {
  const int m = blockIdx.y;
  const int q0 = blockIdx.x * 16;
  const int tid = threadIdx.x;
  const int lane = tid & 63;
  const int wid = tid >> 6;  // 0..7
  const int l15 = lane & 15;
  const int lg = lane >> 4;  // 0..3
  const int kk = wid * 16 + l15;  // dots role: key index in tile (0..127)

  __shared__ u16 q_s[16][264];          // 8448 B
  __shared__ u16 P_s[8][16][136];       // 34816 B
  __shared__ float pmax_s[16][8][8];    // 4096 B
  __shared__ float Mst[16][8];          // 512 B
  __shared__ float xk_s[128][2];        // 1024 B
  __shared__ float W1t[32][12];         // 1536 B  (cols j0,j1,h0..h7,b1,0)
  __shared__ float W2s[32][8];          // 1024 B

  // ---- prologue staging ----
  {
    int r = tid >> 5, cb = (tid & 31) * 8;
    *(s16x8*)&q_s[r][cb] = *(const s16x8*)&qb[((size_t)(m * 1024 + q0 + r)) * 256 + cb];
  }
  if (tid < 384) {
    int c = tid / 12, j = tid - c * 12;
    W1t[c][j] = (j < 10) ? W1[j * 32 + c] : ((j == 10) ? b1[c] : 0.0f);
  }
  if (tid < 256) { W2s[tid >> 3][tid & 7] = W2[tid]; }
  if (tid < 128) { Mst[tid >> 3][tid & 7] = -1e30f; }

  // per-lane tile-invariant values
  float xq0[4], xq1[4];
  #pragma unroll
  for (int i = 0; i < 4; ++i) {
    int qr = lg * 4 + i;
    xq0[i] = xq[((size_t)(m * 1024 + q0 + qr)) * 2 + 0];
    xq1[i] = xq[((size_t)(m * 1024 + q0 + qr)) * 2 + 1];
  }
  const f32x4 b2a = *(const f32x4*)&b2[0];
  const f32x4 b2b = *(const f32x4*)&b2[4];
  s16x8 ones;
  #pragma unroll
  for (int j = 0; j < 8; ++j) ones[j] = (l15 == 0) ? (short)0x3F80 : (short)0;

  f32x4 acc_pv[2];
  acc_pv[0] = (f32x4){0.f, 0.f, 0.f, 0.f};
  acc_pv[1] = (f32x4){0.f, 0.f, 0.f, 0.f};
  f32x4 acc_sum = (f32x4){0.f, 0.f, 0.f, 0.f};
  const f32x4 Z4 = (f32x4){0.f, 0.f, 0.f, 0.f};

  __syncthreads();

  for (int kt = 0; kt < 8; ++kt) {
    const int k0 = kt * 128;
    // ---- stage xk for this tile ----
    if (tid < 256)
      xk_s[tid >> 1][tid & 1] = xkv[((size_t)(m * 1024 + k0 + (tid >> 1))) * 2 + (tid & 1)];
    __syncthreads();  // B1

    // ---- dots: 8 MFMA (one per head), B-frags straight from global (L2) ----
    f32x4 dacc[8];
    #pragma unroll
    for (int h = 0; h < 8; ++h) {
      const s16x8 a = *(const s16x8*)&q_s[l15][h * 32 + lg * 8];
      const s16x8 b = *(const s16x8*)&kb[((size_t)(m * 1024 + k0 + kk)) * 256 + h * 32 + lg * 8];
      dacc[h] = MFMA16(a, b, Z4, 0, 0, 0);
    }

    // ---- kernel MLP (per-lane, 4 pairs each) ----
    const float xk0 = xk_s[kk][0], xk1 = xk_s[kk][1];
    float dq0[4], dq1[4];
    #pragma unroll
    for (int i = 0; i < 4; ++i) { dq0[i] = xq0[i] - xk0; dq1[i] = xq1[i] - xk1; }
    f32x4 lg0[4], lg1[4];
    #pragma unroll
    for (int i = 0; i < 4; ++i) { lg0[i] = b2a; lg1[i] = b2b; }
    #pragma unroll 4
    for (int c = 0; c < 32; ++c) {
      const f32x4 wA = *(const f32x4*)&W1t[c][0];
      const f32x4 wB = *(const f32x4*)&W1t[c][4];
      const f32x4 wC = *(const f32x4*)&W1t[c][8];
      const f32x4 wD = *(const f32x4*)&W2s[c][0];
      const f32x4 wE = *(const f32x4*)&W2s[c][4];
      #pragma unroll
      for (int i = 0; i < 4; ++i) {
        float s = wC[2];
        s = fmaf(dq0[i], wA[0], s);     s = fmaf(dq1[i], wA[1], s);
        s = fmaf(dacc[0][i], wA[2], s); s = fmaf(dacc[1][i], wA[3], s);
        s = fmaf(dacc[2][i], wB[0], s); s = fmaf(dacc[3][i], wB[1], s);
        s = fmaf(dacc[4][i], wB[2], s); s = fmaf(dacc[5][i], wB[3], s);
        s = fmaf(dacc[6][i], wC[0], s); s = fmaf(dacc[7][i], wC[1], s);
        float hv = fmaxf(s, 0.0f);
        lg0[i] += hv * wD;
        lg1[i] += hv * wE;
      }
    }

    // ---- per-(qr,h) tile max across this wave's 16 keys ----
    #pragma unroll
    for (int i = 0; i < 4; ++i) {
      const int qr = lg * 4 + i;
      #pragma unroll
      for (int h = 0; h < 8; ++h) {
        float v = (h < 4) ? lg0[i][h] : lg1[i][h - 4];
        float mx = grp_max16(v);
        if (l15 == 0) pmax_s[qr][h][wid] = mx;
      }
    }
    __syncthreads();  // B2

    // ---- P = exp(logit - mnew) -> bf16 LDS; rescale own-head accumulators ----
    #pragma unroll
    for (int i = 0; i < 4; ++i) {
      const int qr = lg * 4 + i;
      const f32x4 ma = *(const f32x4*)&Mst[qr][0];
      const f32x4 mb = *(const f32x4*)&Mst[qr][4];
      #pragma unroll
      for (int h = 0; h < 8; ++h) {
        const f32x4 p0 = *(const f32x4*)&pmax_s[qr][h][0];
        const f32x4 p1 = *(const f32x4*)&pmax_s[qr][h][4];
        float mt = fmaxf(fmaxf(fmaxf(p0[0], p0[1]), fmaxf(p0[2], p0[3])),
                         fmaxf(fmaxf(p1[0], p1[1]), fmaxf(p1[2], p1[3])));
        float mo = (h < 4) ? ma[h] : mb[h - 4];
        float mn = fmaxf(mo, mt);
        float lv = (h < 4) ? lg0[i][h] : lg1[i][h - 4];
        union { float f; unsigned u; } cv;
        cv.f = __expf(lv - mn);
        P_s[h][qr][kk] = (u16)(cv.u >> 16);
        if (h == wid) {  // wave-uniform branch
          float al = __expf(mo - mn);
          acc_pv[0][i] *= al;
          acc_pv[1][i] *= al;
          acc_sum[i] *= al;
        }
      }
    }
    __syncthreads();  // B3

    // ---- Mst update (wave 0 only; skip on last tile) ----
    if (wid == 0 && kt < 7) {
      #pragma unroll
      for (int i = 0; i < 4; ++i) {
        const int qr = lg * 4 + i;
        #pragma unroll
        for (int h = 0; h < 8; ++h) {
          const f32x4 p0 = *(const f32x4*)&pmax_s[qr][h][0];
          const f32x4 p1 = *(const f32x4*)&pmax_s[qr][h][4];
          float mt = fmaxf(fmaxf(fmaxf(p0[0], p0[1]), fmaxf(p0[2], p0[3])),
                           fmaxf(fmaxf(p1[0], p1[1]), fmaxf(p1[2], p1[3])));
          float mn = fmaxf(Mst[qr][h], mt);
          if (l15 == 0) Mst[qr][h] = mn;
        }
      }
    }

    // ---- PV + sum MFMA: head h = wid, V fragments straight from global ----
    const size_t vbase = ((size_t)(m * 256 + wid * 32)) * 1024 + k0;
    #pragma unroll
    for (int dh = 0; dh < 2; ++dh) {
      #pragma unroll
      for (int ks = 0; ks < 4; ++ks) {
        const s16x8 a = *(const s16x8*)&P_s[wid][l15][ks * 32 + lg * 8];
        const s16x8 b = *(const s16x8*)&vT[vbase + (size_t)(dh * 16 + l15) * 1024 + ks * 32 + lg * 8];
        acc_pv[dh] = MFMA16(a, b, acc_pv[dh], 0, 0, 0);
      }
    }
    #pragma unroll
    for (int ks = 0; ks < 4; ++ks) {
      const s16x8 a = *(const s16x8*)&P_s[wid][l15][ks * 32 + lg * 8];
      acc_sum = MFMA16(a, ones, acc_sum, 0, 0, 0);
    }
  }

  // ---- epilogue: L via ones-column, normalize, store pre (bf16) ----
  if (l15 == 0) {
    #pragma unroll
    for (int i = 0; i < 4; ++i) Mst[lg * 4 + i][wid] = acc_sum[i];
  }
  __syncthreads();
  #pragma unroll
  for (int dh = 0; dh < 2; ++dh)
    #pragma unroll
    for (int i = 0; i < 4; ++i) {
      const int qr = lg * 4 + i;
      float L = Mst[qr][wid];
      float val = acc_pv[dh][i] / L;
      pre[((size_t)(m * 1024 + q0 + qr)) * 256 + wid * 32 + dh * 16 + l15] = f2b(val);
    }
}

// ---------------- output projection: out = pre @ Wout + bout (f32 out) -----
__global__ __launch_bounds__(256) void outp_kernel(
    const u16* __restrict__ pre, const u16* __restrict__ WoT,
    const float* __restrict__ bout, float* __restrict__ out) {
  const int n0 = blockIdx.x * 64;
  const int j0 = blockIdx.y * 64;
  const int tid = threadIdx.x;
  const int lane = tid & 63, wid = tid >> 6;
  const int l15 = lane & 15, lg = lane >> 4;
  const int wn = wid & 1, wj = wid >> 1;
  __shared__ u16 As[64][40];
  __shared__ u16 Bs[64][40];
  f32x4 acc[2][2];
  #pragma unroll
  for (int a = 0; a < 2; ++a)
    #pragma unroll
    for (int b = 0; b < 2; ++b) acc[a][b] = (f32x4){0.f, 0.f, 0.f, 0.f};

  for (int ks = 0; ks < 8; ++ks) {
    const int d0 = ks * 32;
    const int r = tid >> 2, cb = (tid & 3) * 8;
    *(s16x8*)&As[r][cb] = *(const s16x8*)&pre[(size_t)(n0 + r) * 256 + d0 + cb];
    *(s16x8*)&Bs[r][cb] = *(const s16x8*)&WoT[(size_t)(j0 + r) * 256 + d0 + cb];
    __syncthreads();
    s16x8 a0 = *(const s16x8*)&As[wn * 32 + l15][lg * 8];
    s16x8 a1 = *(const s16x8*)&As[wn * 32 + 16 + l15][lg * 8];
    s16x8 b0 = *(const s16x8*)&Bs[wj * 32 + l15][lg * 8];
    s16x8 b1 = *(const s16x8*)&Bs[wj * 32 + 16 + l15][lg * 8];
    acc[0][0] = MFMA16(a0, b0, acc[0][0], 0, 0, 0);
    acc[0][1] = MFMA16(a0, b1, acc[0][1], 0, 0, 0);
    acc[1][0] = MFMA16(a1, b0, acc[1][0], 0, 0, 0);
    acc[1][1] = MFMA16(a1, b1, acc[1][1], 0, 0, 0);
    __syncthreads();
  }
  #pragma unroll
  for (int sn = 0; sn < 2; ++sn)
    #pragma unroll
    for (int sj = 0; sj < 2; ++sj)
      #pragma unroll
      for (int i = 0; i < 4; ++i) {
        int n = n0 + wn * 32 + sn * 16 + lg * 4 + i;
        int j = j0 + wj * 32 + sj * 16 + l15;
        out[(size_t)n * 256 + j] = acc[sn][sj][i] + bout[j];
      }
}

extern "C" void kernel_launch(void* const* d_in, const int* in_sizes, int n_in,
                              void* d_out, int out_size, void* d_ws, size_t ws_size,
                              hipStream_t stream) {
  const float* zq = (const float*)d_in[0];
  const float* zk = (const float*)d_in[1];
  const float* zv = (const float*)d_in[2];
  const float* xq = (const float*)d_in[3];
  const float* xkv = (const float*)d_in[4];
  const float* Wq = (const float*)d_in[5];
  const float* Wk = (const float*)d_in[6];
  const float* Wv = (const float*)d_in[7];
  const float* Wo = (const float*)d_in[8];
  const float* bout = (const float*)d_in[9];
  const float* W1 = (const float*)d_in[10];
  const float* b1 = (const float*)d_in[11];
  const float* W2 = (const float*)d_in[12];
  const float* b2 = (const float*)d_in[13];
  float* out = (float*)d_out;

  char* ws = (char*)d_ws;
  u16* qb  = (u16*)(ws + (size_t)0);
  u16* kb  = (u16*)(ws + ((size_t)4 << 20));
  u16* vT  = (u16*)(ws + ((size_t)8 << 20));
  u16* pre = (u16*)(ws + ((size_t)12 << 20));
  u16* WqT = (u16*)(ws + ((size_t)16 << 20));
  u16* WkT = (u16*)(ws + ((size_t)16 << 20) + (128 << 10));
  u16* WvT = (u16*)(ws + ((size_t)16 << 20) + (256 << 10));
  u16* WoT = (u16*)(ws + ((size_t)16 << 20) + (384 << 10));

  wtrans_kernel<<<dim3(4, 256), dim3(256), 0, stream>>>(Wq, Wk, Wv, Wo, WqT, WkT, WvT, WoT);
  proj_kernel<<<dim3(128, 4, 3), dim3(256), 0, stream>>>(zq, zk, zv, WqT, WkT, WvT, qb, kb, vT);
  attn_kernel<<<dim3(64, 8), dim3(512), 0, stream>>>(qb, kb, vT, xq, xkv, W1, b1, W2, b2, pre);
  outp_kernel<<<dim3(128, 4), dim3(256), 0, stream>>>(pre, WoT, bout, out);
  copyxq_kernel<<<dim3(64), dim3(256), 0, stream>>>(xq, out + (size_t)8 * 1024 * 256);
}

// Round 4
// 149.353 us; speedup vs baseline: 3.3353x; 1.7789x over previous
//
#include <hip/hip_runtime.h>

typedef float f32x4 __attribute__((ext_vector_type(4)));
typedef short s16x8 __attribute__((ext_vector_type(8)));
typedef _Float16 h2 __attribute__((ext_vector_type(2)));
typedef unsigned short u16;

using fp16x2 = decltype(__builtin_amdgcn_cvt_pkrtz(0.0f, 0.0f));

#define MFMA16 __builtin_amdgcn_mfma_f32_16x16x32_bf16
#define SCALE 0.17677669529663687f  // 32^-0.5

#if defined(__has_builtin)
#if __has_builtin(__builtin_amdgcn_fdot2)
#define HAS_FDOT2 1
#endif
#endif

__device__ __forceinline__ h2 cvt_pk(float a, float b) {
  return __builtin_bit_cast(h2, __builtin_amdgcn_cvt_pkrtz(a, b));
}

__device__ __forceinline__ float fdot2f(h2 a, h2 b, float c) {
#ifdef HAS_FDOT2
  return __builtin_amdgcn_fdot2(__builtin_bit_cast(fp16x2, a),
                                __builtin_bit_cast(fp16x2, b), c, false);
#else
  return fmaf((float)a.x, (float)b.x, fmaf((float)a.y, (float)b.y, c));
#endif
}

__device__ __forceinline__ u16 f2b(float f) {
  union { float f; unsigned u; } x; x.f = f;
  unsigned r = x.u + 0x7fffu + ((x.u >> 16) & 1u);
  return (u16)(r >> 16);
}
__device__ __forceinline__ float b2f(u16 s) {
  union { unsigned u; float f; } x; x.u = ((unsigned)s) << 16;
  return x.f;
}

// ---------------- weight transpose + bf16 cast: WT[j][d] = bf16(W[d][j]) ----
__global__ __launch_bounds__(256) void wtrans_kernel(
    const float* __restrict__ Wq, const float* __restrict__ Wk,
    const float* __restrict__ Wv, const float* __restrict__ Wo,
    u16* __restrict__ WqT, u16* __restrict__ WkT,
    u16* __restrict__ WvT, u16* __restrict__ WoT) {
  const float* src; u16* dst;
  switch (blockIdx.x) {
    case 0: src = Wq; dst = WqT; break;
    case 1: src = Wk; dst = WkT; break;
    case 2: src = Wv; dst = WvT; break;
    default: src = Wo; dst = WoT; break;
  }
  int j = blockIdx.y;
  int d = threadIdx.x;
  dst[j * 256 + d] = f2b(src[d * 256 + j]);
}

// ---------------- xq passthrough (output 1) --------------------------------
__global__ __launch_bounds__(256) void copyxq_kernel(const float* __restrict__ xq,
                                                     float* __restrict__ dst) {
  int i = blockIdx.x * 256 + threadIdx.x;
  dst[i] = xq[i];
}

// ---------------- QKV projection: bf16 MFMA GEMM ---------------------------
__global__ __launch_bounds__(256) void proj_kernel(
    const float* __restrict__ zq, const float* __restrict__ zk,
    const float* __restrict__ zv,
    const u16* __restrict__ WqT, const u16* __restrict__ WkT,
    const u16* __restrict__ WvT,
    u16* __restrict__ qb, u16* __restrict__ kb, u16* __restrict__ vT) {
  const int mat = blockIdx.z;
  const float* Z = (mat == 0) ? zq : (mat == 1) ? zk : zv;
  const u16* WT = (mat == 0) ? WqT : (mat == 1) ? WkT : WvT;
  const int n0 = blockIdx.x * 64;
  const int j0 = blockIdx.y * 64;
  const int tid = threadIdx.x;
  const int lane = tid & 63, wid = tid >> 6;
  const int l15 = lane & 15, lg = lane >> 4;
  const int wn = wid & 1, wj = wid >> 1;

  __shared__ u16 As[64][40];
  __shared__ u16 Bs[64][40];

  f32x4 acc[2][2];
  #pragma unroll
  for (int a = 0; a < 2; ++a)
    #pragma unroll
    for (int b = 0; b < 2; ++b) acc[a][b] = (f32x4){0.f, 0.f, 0.f, 0.f};

  for (int ks = 0; ks < 8; ++ks) {
    const int d0 = ks * 32;
    const int r = tid >> 2, cb = (tid & 3) * 8;
    const float* zsrc = &Z[(size_t)(n0 + r) * 256 + d0 + cb];
    s16x8 t;
    #pragma unroll
    for (int j = 0; j < 8; ++j) t[j] = (short)f2b(zsrc[j]);
    *(s16x8*)&As[r][cb] = t;
    *(s16x8*)&Bs[r][cb] = *(const s16x8*)&WT[(size_t)(j0 + r) * 256 + d0 + cb];
    __syncthreads();
    s16x8 a0 = *(const s16x8*)&As[wn * 32 + l15][lg * 8];
    s16x8 a1 = *(const s16x8*)&As[wn * 32 + 16 + l15][lg * 8];
    s16x8 b0 = *(const s16x8*)&Bs[wj * 32 + l15][lg * 8];
    s16x8 b1 = *(const s16x8*)&Bs[wj * 32 + 16 + l15][lg * 8];
    acc[0][0] = MFMA16(a0, b0, acc[0][0], 0, 0, 0);
    acc[0][1] = MFMA16(a0, b1, acc[0][1], 0, 0, 0);
    acc[1][0] = MFMA16(a1, b0, acc[1][0], 0, 0, 0);
    acc[1][1] = MFMA16(a1, b1, acc[1][1], 0, 0, 0);
    __syncthreads();
  }
  #pragma unroll
  for (int sn = 0; sn < 2; ++sn)
    #pragma unroll
    for (int sj = 0; sj < 2; ++sj)
      #pragma unroll
      for (int i = 0; i < 4; ++i) {
        int n = n0 + wn * 32 + sn * 16 + lg * 4 + i;
        int j = j0 + wj * 32 + sj * 16 + l15;
        float av = acc[sn][sj][i];
        if (mat == 0) av *= SCALE;
        u16 val = f2b(av);
        if (mat == 0) {
          qb[(size_t)n * 256 + j] = val;
        } else if (mat == 1) {
          kb[(size_t)n * 256 + j] = val;
        } else {
          int mm = n >> 10, nn = n & 1023;
          vT[((size_t)(mm * 256 + j)) * 1024 + nn] = val;
        }
      }
}

// ---------------- fused TE attention (no-max softmax, k-split) -------------
// Block: 16 queries x 256 keys (kz slice). 512 threads = 8 waves.
// Dots role: wave wid owns keys kk = wid*16+l15. PV role: head h = wid.
__global__ __launch_bounds__(512, 6) void attn_kernel(
    const u16* __restrict__ qb, const u16* __restrict__ kb,
    const u16* __restrict__ vT,
    const float* __restrict__ xq, const float* __restrict__ xkv,
    const float* __restrict__ W1, const float* __restrict__ b1,
    const float* __restrict__ W2, const float* __restrict__ b2,
    u16* __restrict__ preP, float* __restrict__ Lb) {
  const int m = blockIdx.y;
  const int q0 = blockIdx.x * 16;
  const int kz = blockIdx.z;
  const int tid = threadIdx.x;
  const int lane = tid & 63;
  const int wid = tid >> 6;
  const int l15 = lane & 15;
  const int lg = lane >> 4;
  const int kk = wid * 16 + l15;  // key in tile (0..127)

  u16* myPre = preP + (size_t)kz * (8192 * 256);
  float* myL = Lb + (size_t)kz * (8192 * 8);

  __shared__ u16 q_s[16][264];        // 8448 B
  __shared__ u16 P_s[8][16][136];     // 34816 B
  __shared__ unsigned Wc[32][16];     // 2048 B : [0..4]=w1 f16pk, [5]=b1 f32, [8..11]=w2 f16pk

  // ---- prologue ----
  {
    int r = tid >> 5, cb = (tid & 31) * 8;
    *(s16x8*)&q_s[r][cb] = *(const s16x8*)&qb[((size_t)(m * 1024 + q0 + r)) * 256 + cb];
  }
  if (tid < 32) {
    const int c = tid;
    #pragma unroll
    for (int j = 0; j < 5; ++j) {
      h2 p = cvt_pk(W1[(2 * j) * 32 + c], W1[(2 * j + 1) * 32 + c]);
      Wc[c][j] = __builtin_bit_cast(unsigned, p);
    }
    Wc[c][5] = __builtin_bit_cast(unsigned, b1[c]);
    #pragma unroll
    for (int j = 0; j < 4; ++j) {
      h2 p = cvt_pk(W2[c * 8 + 2 * j], W2[c * 8 + 2 * j + 1]);
      Wc[c][8 + j] = __builtin_bit_cast(unsigned, p);
    }
  }

  float xq0[4], xq1[4];
  #pragma unroll
  for (int i = 0; i < 4; ++i) {
    const float2 v = *(const float2*)&xq[((size_t)(m * 1024 + q0 + lg * 4 + i)) * 2];
    xq0[i] = v.x; xq1[i] = v.y;
  }
  h2 b2p[4];
  #pragma unroll
  for (int j = 0; j < 4; ++j) b2p[j] = cvt_pk(b2[2 * j], b2[2 * j + 1]);

  s16x8 ones;
  #pragma unroll
  for (int j = 0; j < 8; ++j) ones[j] = (l15 == 0) ? (short)0x3F80 : (short)0;

  f32x4 acc_pv[2];
  acc_pv[0] = (f32x4){0.f, 0.f, 0.f, 0.f};
  acc_pv[1] = (f32x4){0.f, 0.f, 0.f, 0.f};
  f32x4 acc_sum = (f32x4){0.f, 0.f, 0.f, 0.f};
  const f32x4 Z4 = (f32x4){0.f, 0.f, 0.f, 0.f};

  __syncthreads();

  for (int kt = 0; kt < 2; ++kt) {
    const int kg = kz * 256 + kt * 128;  // global key base of this tile

    // ---- dots: 8 MFMA, q from LDS, k frags from global (L2) ----
    f32x4 dacc[8];
    #pragma unroll
    for (int h = 0; h < 8; ++h) {
      const s16x8 a = *(const s16x8*)&q_s[l15][h * 32 + lg * 8];
      const s16x8 b = *(const s16x8*)&kb[((size_t)(m * 1024 + kg + kk)) * 256 + h * 32 + lg * 8];
      dacc[h] = MFMA16(a, b, Z4, 0, 0, 0);
    }
    // pack dots to f16 pairs: dpk[hp] = (h=2hp, h=2hp+1)
    h2 dpk[4][4];
    #pragma unroll
    for (int hp = 0; hp < 4; ++hp)
      #pragma unroll
      for (int i = 0; i < 4; ++i)
        dpk[hp][i] = cvt_pk(dacc[2 * hp][i], dacc[2 * hp + 1][i]);

    // position diffs (f16 pairs)
    const float2 xk = *(const float2*)&xkv[((size_t)(m * 1024 + kg + kk)) * 2];
    h2 dqpk[4];
    #pragma unroll
    for (int i = 0; i < 4; ++i)
      dqpk[i] = cvt_pk(xq0[i] - xk.x, xq1[i] - xk.y);

    // ---- kernel MLP: dot2 layer-1, pk_fma f16 layer-2 ----
    h2 lgp[4][4];
    #pragma unroll
    for (int i = 0; i < 4; ++i)
      #pragma unroll
      for (int j = 0; j < 4; ++j) lgp[i][j] = b2p[j];

    #pragma unroll 2
    for (int c = 0; c < 32; ++c) {
      const uint4 wa = *(const uint4*)&Wc[c][0];
      const uint2 wb = *(const uint2*)&Wc[c][4];
      const uint4 wcc = *(const uint4*)&Wc[c][8];
      const h2 w10 = __builtin_bit_cast(h2, wa.x), w11 = __builtin_bit_cast(h2, wa.y);
      const h2 w12 = __builtin_bit_cast(h2, wa.z), w13 = __builtin_bit_cast(h2, wa.w);
      const h2 w14 = __builtin_bit_cast(h2, wb.x);
      const float b1c = __builtin_bit_cast(float, wb.y);
      const h2 w20 = __builtin_bit_cast(h2, wcc.x), w21 = __builtin_bit_cast(h2, wcc.y);
      const h2 w22 = __builtin_bit_cast(h2, wcc.z), w23 = __builtin_bit_cast(h2, wcc.w);
      #pragma unroll
      for (int i = 0; i < 4; ++i) {
        float s = fdot2f(dqpk[i], w10, b1c);
        s = fdot2f(dpk[0][i], w11, s);
        s = fdot2f(dpk[1][i], w12, s);
        s = fdot2f(dpk[2][i], w13, s);
        s = fdot2f(dpk[3][i], w14, s);
        const float hv = fmaxf(s, 0.0f);
        const h2 hh = cvt_pk(hv, hv);
        lgp[i][0] += hh * w20;
        lgp[i][1] += hh * w21;
        lgp[i][2] += hh * w22;
        lgp[i][3] += hh * w23;
      }
    }

    // ---- P = exp(logit) -> bf16 LDS (no max subtraction needed) ----
    #pragma unroll
    for (int i = 0; i < 4; ++i) {
      const int qr = lg * 4 + i;
      #pragma unroll
      for (int j = 0; j < 4; ++j) {
        const float e0 = __expf((float)lgp[i][j].x);
        const float e1 = __expf((float)lgp[i][j].y);
        P_s[2 * j][qr][kk] = (u16)(__builtin_bit_cast(unsigned, e0) >> 16);
        P_s[2 * j + 1][qr][kk] = (u16)(__builtin_bit_cast(unsigned, e1) >> 16);
      }
    }
    __syncthreads();  // P written

    // ---- PV + sum MFMA: head h = wid, V frags from global (L2) ----
    s16x8 pa[4];
    #pragma unroll
    for (int ks = 0; ks < 4; ++ks)
      pa[ks] = *(const s16x8*)&P_s[wid][l15][ks * 32 + lg * 8];
    #pragma unroll
    for (int dh = 0; dh < 2; ++dh) {
      const size_t vrow = ((size_t)(m * 256 + wid * 32 + dh * 16 + l15)) * 1024 + kg;
      #pragma unroll
      for (int ks = 0; ks < 4; ++ks) {
        const s16x8 b = *(const s16x8*)&vT[vrow + ks * 32 + lg * 8];
        acc_pv[dh] = MFMA16(pa[ks], b, acc_pv[dh], 0, 0, 0);
      }
    }
    #pragma unroll
    for (int ks = 0; ks < 4; ++ks)
      acc_sum = MFMA16(pa[ks], ones, acc_sum, 0, 0, 0);
    __syncthreads();  // P consumed
  }

  // ---- epilogue: store bf16 partial PV and f32 partial L ----
  #pragma unroll
  for (int dh = 0; dh < 2; ++dh)
    #pragma unroll
    for (int i = 0; i < 4; ++i) {
      const int qr = lg * 4 + i;
      myPre[((size_t)(m * 1024 + q0 + qr)) * 256 + wid * 32 + dh * 16 + l15] = f2b(acc_pv[dh][i]);
    }
  if (l15 == 0) {
    #pragma unroll
    for (int i = 0; i < 4; ++i)
      myL[((size_t)(m * 1024 + q0 + lg * 4 + i)) * 8 + wid] = acc_sum[i];
  }
}

// ---------------- output projection with 4-way partial combine -------------
__global__ __launch_bounds__(256) void outp_kernel(
    const u16* __restrict__ preP, const float* __restrict__ Lb,
    const u16* __restrict__ WoT,
    const float* __restrict__ bout, float* __restrict__ out) {
  const int n0 = blockIdx.x * 64;
  const int j0 = blockIdx.y * 64;
  const int tid = threadIdx.x;
  const int lane = tid & 63, wid = tid >> 6;
  const int l15 = lane & 15, lg = lane >> 4;
  const int wn = wid & 1, wj = wid >> 1;
  __shared__ u16 As[64][40];
  __shared__ u16 Bs[64][40];
  f32x4 acc[2][2];
  #pragma unroll
  for (int a = 0; a < 2; ++a)
    #pragma unroll
    for (int b = 0; b < 2; ++b) acc[a][b] = (f32x4){0.f, 0.f, 0.f, 0.f};

  const size_t PSTRIDE = (size_t)8192 * 256;
  const size_t LSTRIDE = (size_t)8192 * 8;

  for (int ks = 0; ks < 8; ++ks) {
    const int d0 = ks * 32;
    const int r = tid >> 2, cb = (tid & 3) * 8;
    const size_t row = (size_t)(n0 + r);
    // combine partials: head of this K-chunk is exactly ks
    const float Ls = Lb[row * 8 + ks] + Lb[LSTRIDE + row * 8 + ks] +
                     Lb[2 * LSTRIDE + row * 8 + ks] + Lb[3 * LSTRIDE + row * 8 + ks];
    const float inv = 1.0f / Ls;
    const s16x8 p0 = *(const s16x8*)&preP[row * 256 + d0 + cb];
    const s16x8 p1 = *(const s16x8*)&preP[PSTRIDE + row * 256 + d0 + cb];
    const s16x8 p2 = *(const s16x8*)&preP[2 * PSTRIDE + row * 256 + d0 + cb];
    const s16x8 p3 = *(const s16x8*)&preP[3 * PSTRIDE + row * 256 + d0 + cb];
    s16x8 t;
    #pragma unroll
    for (int j = 0; j < 8; ++j) {
      const float v = (b2f((u16)p0[j]) + b2f((u16)p1[j]) + b2f((u16)p2[j]) + b2f((u16)p3[j])) * inv;
      t[j] = (short)f2b(v);
    }
    *(s16x8*)&As[r][cb] = t;
    *(s16x8*)&Bs[r][cb] = *(const s16x8*)&WoT[(size_t)(j0 + r) * 256 + d0 + cb];
    __syncthreads();
    s16x8 a0 = *(const s16x8*)&As[wn * 32 + l15][lg * 8];
    s16x8 a1 = *(const s16x8*)&As[wn * 32 + 16 + l15][lg * 8];
    s16x8 b0 = *(const s16x8*)&Bs[wj * 32 + l15][lg * 8];
    s16x8 b1 = *(const s16x8*)&Bs[wj * 32 + 16 + l15][lg * 8];
    acc[0][0] = MFMA16(a0, b0, acc[0][0], 0, 0, 0);
    acc[0][1] = MFMA16(a0, b1, acc[0][1], 0, 0, 0);
    acc[1][0] = MFMA16(a1, b0, acc[1][0], 0, 0, 0);
    acc[1][1] = MFMA16(a1, b1, acc[1][1], 0, 0, 0);
    __syncthreads();
  }
  #pragma unroll
  for (int sn = 0; sn < 2; ++sn)
    #pragma unroll
    for (int sj = 0; sj < 2; ++sj)
      #pragma unroll
      for (int i = 0; i < 4; ++i) {
        int n = n0 + wn * 32 + sn * 16 + lg * 4 + i;
        int j = j0 + wj * 32 + sj * 16 + l15;
        out[(size_t)n * 256 + j] = acc[sn][sj][i] + bout[j];
      }
}

extern "C" void kernel_launch(void* const* d_in, const int* in_sizes, int n_in,
                              void* d_out, int out_size, void* d_ws, size_t ws_size,
                              hipStream_t stream) {
  const float* zq = (const float*)d_in[0];
  const float* zk = (const float*)d_in[1];
  const float* zv = (const float*)d_in[2];
  const float* xq = (const float*)d_in[3];
  const float* xkv = (const float*)d_in[4];
  const float* Wq = (const float*)d_in[5];
  const float* Wk = (const float*)d_in[6];
  const float* Wv = (const float*)d_in[7];
  const float* Wo = (const float*)d_in[8];
  const float* bout = (const float*)d_in[9];
  const float* W1 = (const float*)d_in[10];
  const float* b1 = (const float*)d_in[11];
  const float* W2 = (const float*)d_in[12];
  const float* b2 = (const float*)d_in[13];
  float* out = (float*)d_out;

  const size_t MB = (size_t)1 << 20;
  char* ws = (char*)d_ws;
  u16* qb   = (u16*)(ws + 0 * MB);
  u16* kb   = (u16*)(ws + 4 * MB);
  u16* vT   = (u16*)(ws + 8 * MB);
  u16* preP = (u16*)(ws + 12 * MB);            // 4 x 4 MB (bf16 partial PV)
  float* Lb = (float*)(ws + 28 * MB);          // 4 x 256 KB (f32 partial L)
  u16* WqT  = (u16*)(ws + 29 * MB + 0 * (128 << 10));
  u16* WkT  = (u16*)(ws + 29 * MB + 1 * (128 << 10));
  u16* WvT  = (u16*)(ws + 29 * MB + 2 * (128 << 10));
  u16* WoT  = (u16*)(ws + 29 * MB + 3 * (128 << 10));

  wtrans_kernel<<<dim3(4, 256), dim3(256), 0, stream>>>(Wq, Wk, Wv, Wo, WqT, WkT, WvT, WoT);
  proj_kernel<<<dim3(128, 4, 3), dim3(256), 0, stream>>>(zq, zk, zv, WqT, WkT, WvT, qb, kb, vT);
  attn_kernel<<<dim3(64, 8, 4), dim3(512), 0, stream>>>(qb, kb, vT, xq, xkv, W1, b1, W2, b2, preP, Lb);
  outp_kernel<<<dim3(128, 4), dim3(256), 0, stream>>>(preP, Lb, WoT, bout, out);
  copyxq_kernel<<<dim3(64), dim3(256), 0, stream>>>(xq, out + (size_t)8 * 1024 * 256);
}